// Round 1
// baseline (1252.860 us; speedup 1.0000x reference)
//
#include <hip/hip_runtime.h>

#define F_IN 128
#define F_HID 16
#define N_CLS 10

// ---------------- degree / norm ----------------

__global__ __launch_bounds__(256) void k_deg_init(int* __restrict__ deg, int n) {
    int i = blockIdx.x * 256 + threadIdx.x;
    if (i < n) deg[i] = 1;  // self-loop contributes 1 to every node
}

__global__ __launch_bounds__(256) void k_deg_count(const int* __restrict__ dst,
                                                   int* __restrict__ deg, int ne) {
    int i = blockIdx.x * 256 + threadIdx.x;
    if (i < ne) atomicAdd(&deg[dst[i]], 1);
}

__global__ __launch_bounds__(256) void k_dinv(const int* __restrict__ deg,
                                              float* __restrict__ dinv, int n) {
    int i = blockIdx.x * 256 + threadIdx.x;
    if (i < n) dinv[i] = rsqrtf((float)deg[i]);  // deg >= 1 always
}

// ---------------- layer 1 linear: h1lin = x @ W1 ----------------
// block = 256 threads = 16 nodes x 16 features; x rows + W1 staged in LDS.

__global__ __launch_bounds__(256) void k_gemm1(const float* __restrict__ x,
                                               const float* __restrict__ W1,
                                               float* __restrict__ h, int n) {
    __shared__ float Ws[F_IN * F_HID];      // 8 KB
    __shared__ float xs[16][F_IN + 1];      // padded to dodge bank conflicts
    for (int i = threadIdx.x; i < F_IN * F_HID; i += 256) Ws[i] = W1[i];
    int node0 = blockIdx.x * 16;
    for (int i = threadIdx.x; i < 16 * F_IN; i += 256) {
        int r = i >> 7, c = i & 127;
        int node = node0 + r;
        xs[r][c] = (node < n) ? x[(size_t)node * F_IN + c] : 0.f;
    }
    __syncthreads();
    int r = threadIdx.x >> 4, f = threadIdx.x & 15;
    int node = node0 + r;
    if (node < n) {
        float acc = 0.f;
#pragma unroll
        for (int k = 0; k < F_IN; ++k) acc = fmaf(xs[r][k], Ws[k * F_HID + f], acc);
        h[node * F_HID + f] = acc;
    }
}

// ---------------- edge aggregation, 16 features (layer 1) ----------------
// thread = (edge, feature); 16 consecutive lanes share an edge -> coalesced
// 64B gather of h[src] and 64B of atomics to agg[dst].

__global__ __launch_bounds__(256) void k_agg16(const int* __restrict__ src,
                                               const int* __restrict__ dst,
                                               const float* __restrict__ dinv,
                                               const float* __restrict__ h,
                                               float* __restrict__ agg, int ne) {
    int tid = blockIdx.x * 256 + threadIdx.x;
    if (tid >= ne * 16) return;
    int e = tid >> 4, f = tid & 15;
    int s = src[e], d = dst[e];
    float w = dinv[s] * dinv[d];
    atomicAdd(&agg[d * 16 + f], h[s * 16 + f] * w);
}

// ---------------- bias + self-loop + relu (in place into agg1) ----------------

__global__ __launch_bounds__(256) void k_relu_bias_self(float* __restrict__ agg,
                                                        const float* __restrict__ hlin,
                                                        const float* __restrict__ dinv,
                                                        const float* __restrict__ b, int n) {
    int tid = blockIdx.x * 256 + threadIdx.x;
    if (tid >= n * 16) return;
    int nid = tid >> 4, f = tid & 15;
    float di = dinv[nid];
    float v = agg[tid] + hlin[tid] * (di * di) + b[f];
    agg[tid] = fmaxf(v, 0.f);
}

// ---------------- layer 2 linear: h2lin = h1 @ W2 ----------------
// one thread per node; W2 (16x10) in LDS; h1 row via 4x float4.

__global__ __launch_bounds__(256) void k_gemm2(const float* __restrict__ h1,
                                               const float* __restrict__ W2,
                                               float* __restrict__ h2, int n) {
    __shared__ float Ws[F_HID * N_CLS];
    if (threadIdx.x < F_HID * N_CLS) Ws[threadIdx.x] = W2[threadIdx.x];
    __syncthreads();
    int nid = blockIdx.x * 256 + threadIdx.x;
    if (nid >= n) return;
    const float4* row = (const float4*)(h1 + nid * 16);
    float4 r0 = row[0], r1 = row[1], r2 = row[2], r3 = row[3];
    float hk[16] = {r0.x, r0.y, r0.z, r0.w, r1.x, r1.y, r1.z, r1.w,
                    r2.x, r2.y, r2.z, r2.w, r3.x, r3.y, r3.z, r3.w};
    float acc[N_CLS];
#pragma unroll
    for (int c = 0; c < N_CLS; ++c) acc[c] = 0.f;
#pragma unroll
    for (int k = 0; k < F_HID; ++k)
#pragma unroll
        for (int c = 0; c < N_CLS; ++c) acc[c] = fmaf(hk[k], Ws[k * N_CLS + c], acc[c]);
#pragma unroll
    for (int c = 0; c < N_CLS; ++c) h2[nid * N_CLS + c] = acc[c];
}

// ---------------- edge aggregation, 10 features (layer 2) ----------------

__global__ __launch_bounds__(256) void k_agg10(const int* __restrict__ src,
                                               const int* __restrict__ dst,
                                               const float* __restrict__ dinv,
                                               const float* __restrict__ h,
                                               float* __restrict__ agg, int ne) {
    int tid = blockIdx.x * 256 + threadIdx.x;
    if (tid >= ne * 10) return;
    int e = tid / 10, c = tid - e * 10;
    int s = src[e], d = dst[e];
    float w = dinv[s] * dinv[d];
    atomicAdd(&agg[d * 10 + c], h[s * 10 + c] * w);
}

// ---------------- self-loop + bias + log_softmax ----------------

__global__ __launch_bounds__(256) void k_final(const float* __restrict__ agg,
                                               const float* __restrict__ hlin,
                                               const float* __restrict__ dinv,
                                               const float* __restrict__ b,
                                               float* __restrict__ out, int n) {
    int nid = blockIdx.x * 256 + threadIdx.x;
    if (nid >= n) return;
    float di = dinv[nid];
    float self = di * di;
    float v[N_CLS];
    float m = -1e30f;
#pragma unroll
    for (int c = 0; c < N_CLS; ++c) {
        v[c] = agg[nid * N_CLS + c] + hlin[nid * N_CLS + c] * self + b[c];
        m = fmaxf(m, v[c]);
    }
    float sum = 0.f;
#pragma unroll
    for (int c = 0; c < N_CLS; ++c) sum += expf(v[c] - m);
    float lse = logf(sum);
#pragma unroll
    for (int c = 0; c < N_CLS; ++c) out[nid * N_CLS + c] = v[c] - m - lse;
}

extern "C" void kernel_launch(void* const* d_in, const int* in_sizes, int n_in,
                              void* d_out, int out_size, void* d_ws, size_t ws_size,
                              hipStream_t stream) {
    const float* x  = (const float*)d_in[0];
    const int*   ei = (const int*)d_in[1];
    const float* W1 = (const float*)d_in[2];
    const float* b1 = (const float*)d_in[3];
    const float* W2 = (const float*)d_in[4];
    const float* b2 = (const float*)d_in[5];
    float* out = (float*)d_out;

    const int n  = in_sizes[0] / F_IN;   // 100000
    const int ne = in_sizes[1] / 2;      // 6400000
    const int* src = ei;                 // edge_index[0]
    const int* dst = ei + ne;            // edge_index[1]

    // workspace carve-up (256B aligned)
    char* ws = (char*)d_ws;
    size_t off = 0;
    auto carve = [&](size_t bytes) -> void* {
        void* p = ws + off;
        off += (bytes + 255) & ~(size_t)255;
        return p;
    };
    int*   degi  = (int*)  carve((size_t)n * 4);
    float* dinv  = (float*)carve((size_t)n * 4);
    float* h1lin = (float*)carve((size_t)n * F_HID * 4);
    float* agg1  = (float*)carve((size_t)n * F_HID * 4);   // becomes h1 after relu
    float* h2lin = (float*)carve((size_t)n * N_CLS * 4);
    float* agg2  = (float*)carve((size_t)n * N_CLS * 4);
    (void)ws_size;

    hipMemsetAsync(agg1, 0, (size_t)n * F_HID * 4, stream);
    hipMemsetAsync(agg2, 0, (size_t)n * N_CLS * 4, stream);

    k_deg_init<<<(n + 255) / 256, 256, 0, stream>>>(degi, n);
    k_deg_count<<<(ne + 255) / 256, 256, 0, stream>>>(dst, degi, ne);
    k_dinv<<<(n + 255) / 256, 256, 0, stream>>>(degi, dinv, n);

    k_gemm1<<<(n + 15) / 16, 256, 0, stream>>>(x, W1, h1lin, n);
    k_agg16<<<(ne * 16 + 255) / 256, 256, 0, stream>>>(src, dst, dinv, h1lin, agg1, ne);
    k_relu_bias_self<<<(n * 16 + 255) / 256, 256, 0, stream>>>(agg1, h1lin, dinv, b1, n);

    k_gemm2<<<(n + 255) / 256, 256, 0, stream>>>(agg1, W2, h2lin, n);
    k_agg10<<<(ne * 10 + 255) / 256, 256, 0, stream>>>(src, dst, dinv, h2lin, agg2, ne);
    k_final<<<(n + 255) / 256, 256, 0, stream>>>(agg2, h2lin, dinv, b2, out, n);
}

// Round 3
// 1010.879 us; speedup vs baseline: 1.2394x; 1.2394x over previous
//
#include <hip/hip_runtime.h>

#define F_IN 128
#define F_HID 16
#define N_CLS 10

// ================= CSR build =================

__global__ __launch_bounds__(256) void k_hist(const int* __restrict__ dst,
                                              int* __restrict__ hist, int ne) {
    int i = blockIdx.x * 256 + threadIdx.x;
    if (i < ne) atomicAdd(&hist[dst[i]], 1);
}

__global__ __launch_bounds__(256) void k_dinv(const int* __restrict__ hist,
                                              float* __restrict__ dinv, int n) {
    int i = blockIdx.x * 256 + threadIdx.x;
    if (i < n) dinv[i] = rsqrtf((float)(hist[i] + 1));  // +1 self-loop
}

// per-block (256) sums of hist -> bsums
__global__ __launch_bounds__(256) void k_breduce(const int* __restrict__ hist,
                                                 int* __restrict__ bsums, int n) {
    int i = blockIdx.x * 256 + threadIdx.x;
    int v = (i < n) ? hist[i] : 0;
#pragma unroll
    for (int d = 32; d >= 1; d >>= 1) v += __shfl_down(v, d);
    __shared__ int ws[4];
    if ((threadIdx.x & 63) == 0) ws[threadIdx.x >> 6] = v;
    __syncthreads();
    if (threadIdx.x == 0) bsums[blockIdx.x] = ws[0] + ws[1] + ws[2] + ws[3];
}

// single-block exclusive scan of bsums (nb <= 1024)
__global__ __launch_bounds__(1024) void k_bscan(int* __restrict__ bsums, int nb) {
    __shared__ int sm[1024];
    int t = threadIdx.x;
    int v = (t < nb) ? bsums[t] : 0;
    sm[t] = v;
    __syncthreads();
    int acc = v;
    for (int d = 1; d < 1024; d <<= 1) {
        int add = (t >= d) ? sm[t - d] : 0;
        __syncthreads();
        acc += add;
        sm[t] = acc;
        __syncthreads();
    }
    if (t < nb) bsums[t] = acc - v;  // exclusive
}

// per-block exclusive scan of hist + block base -> offs
__global__ __launch_bounds__(256) void k_scan2(const int* __restrict__ hist,
                                               const int* __restrict__ bsums,
                                               int* __restrict__ offs, int n) {
    __shared__ int sm[256];
    int t = threadIdx.x;
    int i = blockIdx.x * 256 + t;
    int v = (i < n) ? hist[i] : 0;
    sm[t] = v;
    __syncthreads();
    int acc = v;
    for (int d = 1; d < 256; d <<= 1) {
        int add = (t >= d) ? sm[t - d] : 0;
        __syncthreads();
        acc += add;
        sm[t] = acc;
        __syncthreads();
    }
    if (i < n) offs[i] = acc - v + bsums[blockIdx.x];
}

__global__ __launch_bounds__(256) void k_scatter(const int* __restrict__ src,
                                                 const int* __restrict__ dst,
                                                 const int* __restrict__ offs,
                                                 int* __restrict__ cursor,
                                                 int* __restrict__ csr_src, int ne) {
    int e = blockIdx.x * 256 + threadIdx.x;
    if (e < ne) {
        int d = dst[e];
        int p = offs[d] + atomicAdd(&cursor[d], 1);
        csr_src[p] = src[e];
    }
}

// ================= layer 1 linear: h1lin = x @ W1 =================

__global__ __launch_bounds__(256) void k_gemm1(const float* __restrict__ x,
                                               const float* __restrict__ W1,
                                               float* __restrict__ h, int n) {
    __shared__ float Ws[F_IN * F_HID];
    __shared__ float xs[16][F_IN + 1];
    for (int i = threadIdx.x; i < F_IN * F_HID; i += 256) Ws[i] = W1[i];
    int node0 = blockIdx.x * 16;
    for (int i = threadIdx.x; i < 16 * F_IN; i += 256) {
        int r = i >> 7, c = i & 127;
        int node = node0 + r;
        xs[r][c] = (node < n) ? x[(size_t)node * F_IN + c] : 0.f;
    }
    __syncthreads();
    int r = threadIdx.x >> 4, f = threadIdx.x & 15;
    int node = node0 + r;
    if (node < n) {
        float acc = 0.f;
#pragma unroll
        for (int k = 0; k < F_IN; ++k) acc = fmaf(xs[r][k], Ws[k * F_HID + f], acc);
        h[node * F_HID + f] = acc;
    }
}

// ================= CSR aggregation layer 1 (16 feats) + self + bias + relu ====
// one wave per node: 4 edge slots x 16 features

__global__ __launch_bounds__(256) void k_agg16csr(const int* __restrict__ offs,
                                                  const int* __restrict__ cnts,
                                                  const int* __restrict__ csr,
                                                  const float* __restrict__ dinv,
                                                  const float* __restrict__ hin,
                                                  const float* __restrict__ b,
                                                  float* __restrict__ hout, int n) {
    int node = blockIdx.x * 4 + (threadIdx.x >> 6);
    if (node >= n) return;
    int lane = threadIdx.x & 63;
    int slot = lane >> 4, f = lane & 15;
    int off = offs[node], cnt = cnts[node];
    float acc = 0.f;
    for (int i = slot; i < cnt; i += 4) {
        int s = csr[off + i];
        acc += hin[s * 16 + f] * dinv[s];
    }
    acc += __shfl_xor(acc, 16);
    acc += __shfl_xor(acc, 32);
    if (slot == 0) {
        float dd = dinv[node];
        float v = acc * dd + hin[node * 16 + f] * (dd * dd) + b[f];
        hout[node * 16 + f] = fmaxf(v, 0.f);
    }
}

// ================= layer 2 linear: h2lin = h1 @ W2 =================

__global__ __launch_bounds__(256) void k_gemm2(const float* __restrict__ h1,
                                               const float* __restrict__ W2,
                                               float* __restrict__ h2, int n) {
    __shared__ float Ws[F_HID * N_CLS];
    if (threadIdx.x < F_HID * N_CLS) Ws[threadIdx.x] = W2[threadIdx.x];
    __syncthreads();
    int nid = blockIdx.x * 256 + threadIdx.x;
    if (nid >= n) return;
    const float4* row = (const float4*)(h1 + nid * 16);
    float4 r0 = row[0], r1 = row[1], r2 = row[2], r3 = row[3];
    float hk[16] = {r0.x, r0.y, r0.z, r0.w, r1.x, r1.y, r1.z, r1.w,
                    r2.x, r2.y, r2.z, r2.w, r3.x, r3.y, r3.z, r3.w};
    float acc[N_CLS];
#pragma unroll
    for (int c = 0; c < N_CLS; ++c) acc[c] = 0.f;
#pragma unroll
    for (int k = 0; k < F_HID; ++k)
#pragma unroll
        for (int c = 0; c < N_CLS; ++c) acc[c] = fmaf(hk[k], Ws[k * N_CLS + c], acc[c]);
#pragma unroll
    for (int c = 0; c < N_CLS; ++c) h2[nid * N_CLS + c] = acc[c];
}

// ================= CSR aggregation layer 2 (10 feats) + self + bias ==========

__global__ __launch_bounds__(256) void k_agg10csr(const int* __restrict__ offs,
                                                  const int* __restrict__ cnts,
                                                  const int* __restrict__ csr,
                                                  const float* __restrict__ dinv,
                                                  const float* __restrict__ hin,
                                                  const float* __restrict__ b,
                                                  float* __restrict__ vout, int n) {
    int node = blockIdx.x * 4 + (threadIdx.x >> 6);
    if (node >= n) return;
    int lane = threadIdx.x & 63;
    int slot = lane >> 4, f = lane & 15;
    int off = offs[node], cnt = cnts[node];
    float acc = 0.f;
    if (f < N_CLS) {
        for (int i = slot; i < cnt; i += 4) {
            int s = csr[off + i];
            acc += hin[s * N_CLS + f] * dinv[s];
        }
    }
    acc += __shfl_xor(acc, 16);
    acc += __shfl_xor(acc, 32);
    if (slot == 0 && f < N_CLS) {
        float dd = dinv[node];
        vout[node * N_CLS + f] = acc * dd + hin[node * N_CLS + f] * (dd * dd) + b[f];
    }
}

// ================= log_softmax =================

__global__ __launch_bounds__(256) void k_logsoftmax(const float* __restrict__ v,
                                                    float* __restrict__ out, int n) {
    int nid = blockIdx.x * 256 + threadIdx.x;
    if (nid >= n) return;
    float vv[N_CLS];
    float m = -1e30f;
#pragma unroll
    for (int c = 0; c < N_CLS; ++c) {
        vv[c] = v[nid * N_CLS + c];
        m = fmaxf(m, vv[c]);
    }
    float sum = 0.f;
#pragma unroll
    for (int c = 0; c < N_CLS; ++c) sum += expf(vv[c] - m);
    float lse = logf(sum);
#pragma unroll
    for (int c = 0; c < N_CLS; ++c) out[nid * N_CLS + c] = vv[c] - m - lse;
}

extern "C" void kernel_launch(void* const* d_in, const int* in_sizes, int n_in,
                              void* d_out, int out_size, void* d_ws, size_t ws_size,
                              hipStream_t stream) {
    const float* x  = (const float*)d_in[0];
    const int*   ei = (const int*)d_in[1];
    const float* W1 = (const float*)d_in[2];
    const float* b1 = (const float*)d_in[3];
    const float* W2 = (const float*)d_in[4];
    const float* b2 = (const float*)d_in[5];
    float* out = (float*)d_out;

    const int n  = in_sizes[0] / F_IN;   // 100000
    const int ne = in_sizes[1] / 2;      // 6400000
    const int* src = ei;
    const int* dst = ei + ne;

    char* ws = (char*)d_ws;
    size_t off = 0;
    auto carve = [&](size_t bytes) -> void* {
        void* p = ws + off;
        off += (bytes + 255) & ~(size_t)255;
        return p;
    };
    int*   hist    = (int*)  carve((size_t)n * 4);
    int*   offs    = (int*)  carve((size_t)n * 4);
    int*   cursor  = (int*)  carve((size_t)n * 4);
    float* dinv    = (float*)carve((size_t)n * 4);
    int*   bsums   = (int*)  carve(1024 * 4);
    int*   csr_src = (int*)  carve((size_t)ne * 4);
    float* h1lin   = (float*)carve((size_t)n * F_HID * 4);
    float* h1      = (float*)carve((size_t)n * F_HID * 4);
    float* h2lin   = (float*)carve((size_t)n * N_CLS * 4);
    float* v2      = h1lin;  // reuse: h1lin dead after k_agg16csr
    (void)ws_size;

    const int nb = (n + 255) / 256;  // 391 blocks <= 1024

    hipMemsetAsync(hist, 0, (size_t)n * 4, stream);
    hipMemsetAsync(cursor, 0, (size_t)n * 4, stream);

    k_hist<<<(ne + 255) / 256, 256, 0, stream>>>(dst, hist, ne);
    k_dinv<<<nb, 256, 0, stream>>>(hist, dinv, n);
    k_breduce<<<nb, 256, 0, stream>>>(hist, bsums, n);
    k_bscan<<<1, 1024, 0, stream>>>(bsums, nb);
    k_scan2<<<nb, 256, 0, stream>>>(hist, bsums, offs, n);
    k_scatter<<<(ne + 255) / 256, 256, 0, stream>>>(src, dst, offs, cursor, csr_src, ne);

    k_gemm1<<<(n + 15) / 16, 256, 0, stream>>>(x, W1, h1lin, n);
    k_agg16csr<<<(n + 3) / 4, 256, 0, stream>>>(offs, hist, csr_src, dinv, h1lin, b1, h1, n);
    k_gemm2<<<nb, 256, 0, stream>>>(h1, W2, h2lin, n);
    k_agg10csr<<<(n + 3) / 4, 256, 0, stream>>>(offs, hist, csr_src, dinv, h2lin, b2, v2, n);
    k_logsoftmax<<<nb, 256, 0, stream>>>(v2, out, n);
}